// Round 2
// baseline (113.007 us; speedup 1.0000x reference)
//
#include <hip/hip_runtime.h>
#include <math.h>

#define FEAS 4096
#define K 64
#define BATCH 4096

typedef float f4 __attribute__((ext_vector_type(4)));

// ws layout (floats): [0..63] col_sum, [64] diag (sum of squares)

__global__ __launch_bounds__(256) void cross_reduce_kernel(
    const float* __restrict__ cross, float* __restrict__ ws) {
    // 64 blocks x 256 threads; block b handles rows [b*64, b*64+64) of V (4096x64).
    // float4 loads: thread covers col group cg = tid&15 (cols 4cg..4cg+3).
    const int tid = threadIdx.x;
    const int cg  = tid & 15;           // column group (4 cols)
    const int r0  = tid >> 4;           // row-in-block 0..15
    const int row0 = blockIdx.x * 64;

    f4 s = {0.f, 0.f, 0.f, 0.f};
    float q = 0.f;
#pragma unroll
    for (int i = 0; i < 4; ++i) {
        const int r = row0 + r0 + i * 16;
        const f4 v = *(const f4*)(cross + (size_t)r * K + cg * 4);
        s += v;
        q += v.x * v.x + v.y * v.y + v.z * v.z + v.w * v.w;
    }

    // Reduce over lanes sharing the same cg: lanes {cg, cg+16, cg+32, cg+48}.
    s.x += __shfl_xor(s.x, 16, 64); s.y += __shfl_xor(s.y, 16, 64);
    s.z += __shfl_xor(s.z, 16, 64); s.w += __shfl_xor(s.w, 16, 64);
    s.x += __shfl_xor(s.x, 32, 64); s.y += __shfl_xor(s.y, 32, 64);
    s.z += __shfl_xor(s.z, 32, 64); s.w += __shfl_xor(s.w, 32, 64);
    // q: full-wave butterfly.
#pragma unroll
    for (int m = 32; m; m >>= 1) q += __shfl_xor(q, m, 64);

    __shared__ f4 lss[4][16];
    __shared__ float lqq[4];
    const int wv   = tid >> 6;
    const int lane = tid & 63;
    if (lane < 16) lss[wv][lane] = s;   // lane == cg here
    if (lane == 0) lqq[wv] = q;
    __syncthreads();

    if (tid < 16) {
        f4 t4 = lss[0][tid];
        t4 += lss[1][tid]; t4 += lss[2][tid]; t4 += lss[3][tid];
        atomicAdd(&ws[tid * 4 + 0], t4.x);
        atomicAdd(&ws[tid * 4 + 1], t4.y);
        atomicAdd(&ws[tid * 4 + 2], t4.z);
        atomicAdd(&ws[tid * 4 + 3], t4.w);
    } else if (tid == 16) {
        atomicAdd(&ws[64], lqq[0] + lqq[1] + lqq[2] + lqq[3]);
    }
}

// Wave-per-row GEMV: no LDS, no __syncthreads.
// v2: 4 independent FMA accumulators (breaks the 64-deep serial chain),
// nontemporal loads for the streamed-once x matrix.
__global__ __launch_bounds__(256) void gemv_sigmoid_kernel(
    const float* __restrict__ x, const float* __restrict__ w,
    const float* __restrict__ bias, const float* __restrict__ ws,
    float* __restrict__ out) {
    const int lane = threadIdx.x & 63;
    const int row  = blockIdx.x * 4 + (threadIdx.x >> 6);  // 1024 blocks * 4 waves

    // cross_sum + bias, recomputed per wave from ws (65 floats, L2-hot).
    const float c = ws[lane];
    float t = c * c;
#pragma unroll
    for (int m = 32; m; m >>= 1) t += __shfl_xor(t, m, 64);
    const float add = 0.5f * (t + ws[64]) + bias[0];

    const f4* __restrict__ xr = (const f4*)(x + (size_t)row * FEAS);
    const f4* __restrict__ wv = (const f4*)w;

    float a0 = 0.f, a1 = 0.f, a2 = 0.f, a3 = 0.f;
#pragma unroll
    for (int i = 0; i < 16; ++i) {
        const f4 a = __builtin_nontemporal_load(xr + i * 64 + lane);  // streamed once
        const f4 b = wv[i * 64 + lane];                               // L1-resident 16 KiB
        a0 = fmaf(a.x, b.x, a0);
        a1 = fmaf(a.y, b.y, a1);
        a2 = fmaf(a.z, b.z, a2);
        a3 = fmaf(a.w, b.w, a3);
    }
    float acc = (a0 + a1) + (a2 + a3);

#pragma unroll
    for (int m = 32; m; m >>= 1) acc += __shfl_xor(acc, m, 64);

    if (lane == 0) {
        const float y = acc + add;
        out[row] = 1.0f / (1.0f + expf(-y));
    }
}

extern "C" void kernel_launch(void* const* d_in, const int* in_sizes, int n_in,
                              void* d_out, int out_size, void* d_ws, size_t ws_size,
                              hipStream_t stream) {
    const float* x     = (const float*)d_in[0];  // (4096, 4096)
    const float* cross = (const float*)d_in[1];  // (4096, 1, 64)
    const float* w     = (const float*)d_in[2];  // (1, 4096)
    const float* b     = (const float*)d_in[3];  // (1,)
    float* out = (float*)d_out;                  // (4096, 1)
    float* ws  = (float*)d_ws;

    // ws is re-poisoned to 0xAA before every timed launch: zero what we use.
    hipMemsetAsync(ws, 0, 65 * sizeof(float), stream);

    cross_reduce_kernel<<<64, 256, 0, stream>>>(cross, ws);
    gemv_sigmoid_kernel<<<BATCH / 4, 256, 0, stream>>>(x, w, b, ws, out);
}

// Round 3
// 99.978 us; speedup vs baseline: 1.1303x; 1.1303x over previous
//
#include <hip/hip_runtime.h>
#include <math.h>

#define FEAS 4096
#define K 64
#define BATCH 4096

typedef float f4 __attribute__((ext_vector_type(4)));

// ws layout (floats): 64 partial blocks, stride 68.
//   ws[p*68 + j]  (j=0..63) = partial column sum of rows [p*64, p*64+64)
//   ws[p*68 + 64]           = partial sum of squares for those rows
// No memset, no atomics: every slot read is written exactly once.

__global__ __launch_bounds__(256) void cross_reduce_kernel(
    const float* __restrict__ cross, float* __restrict__ ws) {
    // 64 blocks x 256 threads; block p handles rows [p*64, p*64+64) of V (4096x64)
    const int tid   = threadIdx.x;
    const int j     = tid & 63;   // column 0..63
    const int rlane = tid >> 6;   // 0..3
    const int row0  = blockIdx.x * 64;

    float s = 0.f, q = 0.f;
#pragma unroll
    for (int i = 0; i < 16; ++i) {
        const int r = row0 + rlane + i * 4;
        const float v = cross[r * K + j];
        s += v;
        q += v * v;
    }

    __shared__ float ls[256];
    __shared__ float lq[256];
    ls[tid] = s;
    lq[tid] = q;
    __syncthreads();

    if (tid < 64) {  // wave 0 only
        const float cs = ls[j] + ls[j + 64] + ls[j + 128] + ls[j + 192];
        ws[blockIdx.x * 68 + j] = cs;

        float cq = lq[j] + lq[j + 64] + lq[j + 128] + lq[j + 192];
#pragma unroll
        for (int off = 32; off; off >>= 1) cq += __shfl_down(cq, off, 64);
        if (j == 0) ws[blockIdx.x * 68 + 64] = cq;
    }
}

// Wave-per-row GEMV: no LDS, no __syncthreads, no dependence on a memset.
__global__ __launch_bounds__(256) void gemv_sigmoid_kernel(
    const float* __restrict__ x, const float* __restrict__ w,
    const float* __restrict__ bias, const float* __restrict__ ws,
    float* __restrict__ out) {
    const int lane = threadIdx.x & 63;
    const int row  = blockIdx.x * 4 + (threadIdx.x >> 6);  // 1024 blocks * 4 waves

    // Prologue: reduce the 64 partial blocks (L2-hot, ~17 KiB working set).
    // lane j accumulates column-sum j; lane p also grabs partial sumsq p.
    float cs = 0.f;
#pragma unroll 8
    for (int p = 0; p < 64; ++p) cs += ws[p * 68 + lane];
    const float qv = ws[lane * 68 + 64];

    // Fused butterfly: sum_j cs_j^2 and sum_p q_p reduce over the same 64 lanes.
    float t = cs * cs + qv;
#pragma unroll
    for (int m = 32; m; m >>= 1) t += __shfl_xor(t, m, 64);
    const float add = 0.5f * t + bias[0];

    const f4* __restrict__ xr = (const f4*)(x + (size_t)row * FEAS);
    const f4* __restrict__ wv = (const f4*)w;

    float a0 = 0.f, a1 = 0.f, a2 = 0.f, a3 = 0.f;
#pragma unroll
    for (int i = 0; i < 16; ++i) {
        const f4 a = xr[i * 64 + lane];  // coalesced: 64 lanes * 16 B = 1 KiB/instr
        const f4 b = wv[i * 64 + lane];  // L1/L2-resident (16 KiB, reused by all waves)
        a0 = fmaf(a.x, b.x, a0);
        a1 = fmaf(a.y, b.y, a1);
        a2 = fmaf(a.z, b.z, a2);
        a3 = fmaf(a.w, b.w, a3);
    }
    float acc = (a0 + a1) + (a2 + a3);

#pragma unroll
    for (int m = 32; m; m >>= 1) acc += __shfl_xor(acc, m, 64);

    if (lane == 0) {
        out[row] = 1.0f / (1.0f + expf(-(acc + add)));
    }
}

extern "C" void kernel_launch(void* const* d_in, const int* in_sizes, int n_in,
                              void* d_out, int out_size, void* d_ws, size_t ws_size,
                              hipStream_t stream) {
    const float* x     = (const float*)d_in[0];  // (4096, 4096)
    const float* cross = (const float*)d_in[1];  // (4096, 1, 64)
    const float* w     = (const float*)d_in[2];  // (1, 4096)
    const float* b     = (const float*)d_in[3];  // (1,)
    float* out = (float*)d_out;                  // (4096, 1)
    float* ws  = (float*)d_ws;

    // ws is poisoned each iteration, but every slot we read is written first
    // by cross_reduce_kernel — no memset, no atomics needed.
    cross_reduce_kernel<<<64, 256, 0, stream>>>(cross, ws);
    gemv_sigmoid_kernel<<<BATCH / 4, 256, 0, stream>>>(x, w, b, ws, out);
}